// Round 1
// 527.418 us; speedup vs baseline: 1.0499x; 1.0499x over previous
//
#include <hip/hip_runtime.h>

// TernaryLinear: out = x @ (sign(W1)-sign(W2)).T + (b1-b2)
// M=8192 tokens, N=4096 out, K=4096 in. One f16-MFMA GEMM after folding.
//
// GEMM structure: 256x256 tile, BK=64, 512 threads = 8 waves (2M x 4N),
// 8-phase-per-2-K-tiles schedule (here written as 4 phases per K-tile),
// counted vmcnt (never 0 in main loop), setprio around MFMA clusters,
// XOR-swizzled LDS (chunk ^= row&7, applied on the global source for the
// linear global_load_lds dest and on the ds_read side), XCD-bijective
// block swizzle. LDS 128 KiB double-buffered (A: 2x32K, B: 2x32K).

#define DIM_K 4096
#define DIM_N 4096
#define DIM_M 8192

typedef _Float16 f16x8 __attribute__((ext_vector_type(8)));
typedef float    f32x4 __attribute__((ext_vector_type(4)));

// ---------------- fused conversion kernel ----------------
// units of 8 elements; x-units first, then W-units.
// x: f32 -> f16.  W: sign(W1)-sign(W2) in {-2..2} -> f16 exact.

__device__ __forceinline__ float signdiff(float a, float b) {
    const float sa = (float)((a > 0.f) - (a < 0.f));
    const float sb = (float)((b > 0.f) - (b < 0.f));
    return sa - sb;
}

__global__ void cvt_fused(const float4* __restrict__ x,
                          const float4* __restrict__ w1,
                          const float4* __restrict__ w2,
                          f16x8* __restrict__ xh,
                          f16x8* __restrict__ wh) {
    const int XU = DIM_M * DIM_K / 8;           // 4194304
    const int TU = XU + DIM_N * DIM_K / 8;      // 6291456
    const int stride = gridDim.x * blockDim.x;  // 524288 -> 12 iters
    for (int u = blockIdx.x * blockDim.x + threadIdx.x; u < TU; u += stride) {
        if (u < XU) {
            const float4 a = x[2 * u], b = x[2 * u + 1];
            f16x8 h;
            h[0] = (_Float16)a.x; h[1] = (_Float16)a.y;
            h[2] = (_Float16)a.z; h[3] = (_Float16)a.w;
            h[4] = (_Float16)b.x; h[5] = (_Float16)b.y;
            h[6] = (_Float16)b.z; h[7] = (_Float16)b.w;
            xh[u] = h;
        } else {
            const int v = u - XU;
            const float4 a1 = w1[2 * v], b1 = w1[2 * v + 1];
            const float4 a2 = w2[2 * v], b2 = w2[2 * v + 1];
            f16x8 h;
            h[0] = (_Float16)signdiff(a1.x, a2.x);
            h[1] = (_Float16)signdiff(a1.y, a2.y);
            h[2] = (_Float16)signdiff(a1.z, a2.z);
            h[3] = (_Float16)signdiff(a1.w, a2.w);
            h[4] = (_Float16)signdiff(b1.x, b2.x);
            h[5] = (_Float16)signdiff(b1.y, b2.y);
            h[6] = (_Float16)signdiff(b1.z, b2.z);
            h[7] = (_Float16)signdiff(b1.w, b2.w);
            wh[v] = h;
        }
    }
}

// ---------------- GEMM ----------------
// Schedule invariants (per K-tile kt, buffers buf[kt&1]):
//   p0: ds_read A-blk0(8) + B-blk0(4); stage A-half1(kt+1)
//   p1: ds_read B-blk1(4);             stage B-half1(kt+1)
//   p2: ds_read A-blk1(8);             stage A-half0(kt+2)   <- slot freed at p0
//   p3: (regs resident);               stage B-half0(kt+2)   <- slot freed at p0
//   end of p3: s_waitcnt vmcnt(4)  => all 4 halves of kt+1 landed,
//              2 half-tiles (kt+2 A0/B0) stay in flight across the barrier.
// Halves: A-half0 = rows [0,128) = both waves' im0..3 blocks (wave wm owns
// rows wm*64+[0,64) and 128+wm*64+[0,64)), so each half's read-live window
// is only the two phases that touch it -> restaging mid-tile is race-free
// (protected by the previous phase's post-MFMA barrier).

__global__ __launch_bounds__(512, 2) void ternary_gemm(
    const _Float16* __restrict__ Xh, const _Float16* __restrict__ Wh,
    const float* __restrict__ B1, const float* __restrict__ B2,
    float* __restrict__ C) {
    __shared__ __align__(16) char smem[131072];
    // A buffers at 0 / 32K; B buffers at 64K / 96K. Buffer = [256][64] f16,
    // row stride 128 B, physical chunk = logical chunk ^ (row&7).

    const int tid  = threadIdx.x;
    const int wave = tid >> 6;
    const int lane = tid & 63;
    const int wm = wave >> 2;      // 0..1
    const int wn = wave & 3;       // 0..3
    const int q  = lane >> 4;      // 0..3
    const int r  = lane & 15;

    // XCD-bijective block swizzle: nwg = 512 = 8 * 64
    const int bid = blockIdx.x;
    const int id  = (bid & 7) * 64 + (bid >> 3);
    const int bRowM = (id >> 4) * 256;   // 32 M-tiles
    const int bColN = (id & 15) * 256;   // 16 N-tiles

    // ---- staging geometry ----
    const int srow   = tid >> 3;                     // 0..63 row within 64-row issue
    const int gchunk = (tid & 7) ^ (srow & 7);       // pre-swizzled global chunk
    const char* aSrc = (const char*)Xh + (size_t)(bRowM + srow) * (DIM_K * 2) + gchunk * 16;
    const char* bSrc = (const char*)Wh + (size_t)(bColN + srow) * (DIM_K * 2) + gchunk * 16;
    char* const ldsBase = smem;
    const int waveOff = wave * 1024;                 // wave-uniform LDS base part

#define STAGE_A(bufsel, h, dk) do {                                                             \
    _Pragma("unroll")                                                                           \
    for (int i_ = 0; i_ < 2; ++i_)                                                              \
        __builtin_amdgcn_global_load_lds(                                                       \
            (const __attribute__((address_space(1))) void*)(                                    \
                aSrc + (size_t)((h) * 128 + i_ * 64) * (DIM_K * 2) + (dk) * 128),               \
            (__attribute__((address_space(3))) void*)(                                          \
                ldsBase + (bufsel) * 32768 + ((h) * 128 + i_ * 64) * 128 + waveOff),            \
            16, 0, 0);                                                                          \
} while (0)
#define STAGE_B(bufsel, h, dk) do {                                                             \
    _Pragma("unroll")                                                                           \
    for (int i_ = 0; i_ < 2; ++i_)                                                              \
        __builtin_amdgcn_global_load_lds(                                                       \
            (const __attribute__((address_space(1))) void*)(                                    \
                bSrc + (size_t)((h) * 128 + i_ * 64) * (DIM_K * 2) + (dk) * 128),               \
            (__attribute__((address_space(3))) void*)(                                          \
                ldsBase + 65536 + (bufsel) * 32768 + ((h) * 128 + i_ * 64) * 128 + waveOff),    \
            16, 0, 0);                                                                          \
} while (0)

    // ---- compute-side LDS read bases ----
    const int swz = r & 7;
    char* const aRd = smem + (wm * 64 + r) * 128;            // A half0 base for this wave
    char* const bRd = smem + 65536 + (wn * 32 + r) * 128;    // B half0 base
    const int ck0 = ((0 * 4 + q) ^ swz) * 16;
    const int ck1 = ((1 * 4 + q) ^ swz) * 16;

    f32x4 acc[2][2][4][2] = {};   // [mhalf][nhalf][im][in]
    f16x8 af[4][2], bf0[2][2], bf1[2][2];

    // ---- prologue: kt0 fully, kt1 A0/B0 (order matters for vmcnt counts) ----
    STAGE_A(0, 0, 0);
    STAGE_B(0, 0, 0);
    STAGE_A(0, 1, 0);
    STAGE_B(0, 1, 0);
    STAGE_A(1, 0, 1);
    STAGE_B(1, 0, 1);
    asm volatile("s_waitcnt vmcnt(4)" ::: "memory");  // kt0's 4 halves landed
    __builtin_amdgcn_s_barrier();
    __builtin_amdgcn_sched_barrier(0);

    for (int kt = 0; kt < 64; ++kt) {
        const int cur = kt & 1, nxt = cur ^ 1;
        const char* const aC = aRd + cur * 32768;
        const char* const bC = bRd + cur * 32768;

        // ---------- phase 0: A-blk0 + B-blk0 ----------
#pragma unroll
        for (int im = 0; im < 4; ++im) {
            af[im][0] = *(const f16x8*)(aC + im * 2048 + ck0);
            af[im][1] = *(const f16x8*)(aC + im * 2048 + ck1);
        }
#pragma unroll
        for (int in = 0; in < 2; ++in) {
            bf0[in][0] = *(const f16x8*)(bC + in * 2048 + ck0);
            bf0[in][1] = *(const f16x8*)(bC + in * 2048 + ck1);
        }
        if (kt < 63) STAGE_A(nxt, 1, 1);
        __builtin_amdgcn_s_barrier();
        asm volatile("s_waitcnt lgkmcnt(0)" ::: "memory");
        __builtin_amdgcn_sched_barrier(0);
        __builtin_amdgcn_s_setprio(1);
#pragma unroll
        for (int im = 0; im < 4; ++im)
#pragma unroll
            for (int in = 0; in < 2; ++in)
#pragma unroll
                for (int kk = 0; kk < 2; ++kk)
                    acc[0][0][im][in] = __builtin_amdgcn_mfma_f32_16x16x32_f16(
                        af[im][kk], bf0[in][kk], acc[0][0][im][in], 0, 0, 0);
        __builtin_amdgcn_s_setprio(0);
        __builtin_amdgcn_sched_barrier(0);
        __builtin_amdgcn_s_barrier();
        __builtin_amdgcn_sched_barrier(0);

        // ---------- phase 1: B-blk1 (A-blk0 resident) ----------
#pragma unroll
        for (int in = 0; in < 2; ++in) {
            bf1[in][0] = *(const f16x8*)(bC + 16384 + in * 2048 + ck0);
            bf1[in][1] = *(const f16x8*)(bC + 16384 + in * 2048 + ck1);
        }
        if (kt < 63) STAGE_B(nxt, 1, 1);
        __builtin_amdgcn_s_barrier();
        asm volatile("s_waitcnt lgkmcnt(0)" ::: "memory");
        __builtin_amdgcn_sched_barrier(0);
        __builtin_amdgcn_s_setprio(1);
#pragma unroll
        for (int im = 0; im < 4; ++im)
#pragma unroll
            for (int in = 0; in < 2; ++in)
#pragma unroll
                for (int kk = 0; kk < 2; ++kk)
                    acc[0][1][im][in] = __builtin_amdgcn_mfma_f32_16x16x32_f16(
                        af[im][kk], bf1[in][kk], acc[0][1][im][in], 0, 0, 0);
        __builtin_amdgcn_s_setprio(0);
        __builtin_amdgcn_sched_barrier(0);
        __builtin_amdgcn_s_barrier();
        __builtin_amdgcn_sched_barrier(0);

        // ---------- phase 2: A-blk1 (B-blk0 resident) ----------
#pragma unroll
        for (int im = 0; im < 4; ++im) {
            af[im][0] = *(const f16x8*)(aC + 16384 + im * 2048 + ck0);
            af[im][1] = *(const f16x8*)(aC + 16384 + im * 2048 + ck1);
        }
        if (kt < 62) STAGE_A(cur, 0, 2);
        __builtin_amdgcn_s_barrier();
        asm volatile("s_waitcnt lgkmcnt(0)" ::: "memory");
        __builtin_amdgcn_sched_barrier(0);
        __builtin_amdgcn_s_setprio(1);
#pragma unroll
        for (int im = 0; im < 4; ++im)
#pragma unroll
            for (int in = 0; in < 2; ++in)
#pragma unroll
                for (int kk = 0; kk < 2; ++kk)
                    acc[1][0][im][in] = __builtin_amdgcn_mfma_f32_16x16x32_f16(
                        af[im][kk], bf0[in][kk], acc[1][0][im][in], 0, 0, 0);
        __builtin_amdgcn_s_setprio(0);
        __builtin_amdgcn_sched_barrier(0);
        __builtin_amdgcn_s_barrier();
        __builtin_amdgcn_sched_barrier(0);

        // ---------- phase 3: all resident; counted vmcnt gate ----------
        if (kt < 62) STAGE_B(cur, 0, 2);
        __builtin_amdgcn_s_barrier();
        __builtin_amdgcn_s_setprio(1);
#pragma unroll
        for (int im = 0; im < 4; ++im)
#pragma unroll
            for (int in = 0; in < 2; ++in)
#pragma unroll
                for (int kk = 0; kk < 2; ++kk)
                    acc[1][1][im][in] = __builtin_amdgcn_mfma_f32_16x16x32_f16(
                        af[im][kk], bf1[in][kk], acc[1][1][im][in], 0, 0, 0);
        __builtin_amdgcn_s_setprio(0);
        if (kt < 62) {
            asm volatile("s_waitcnt vmcnt(4)" ::: "memory");   // kt+1 landed, kt+2 A0/B0 in flight
        } else if (kt == 62) {
            asm volatile("s_waitcnt vmcnt(0)" ::: "memory");   // epilogue drain: kt63 landed
        }
        __builtin_amdgcn_s_barrier();
        __builtin_amdgcn_sched_barrier(0);

        aSrc += 128;   // advance one K-tile (64 halves)
        bSrc += 128;
    }

    // ---- epilogue: C/D layout col=lane&15, row=(lane>>4)*4+reg; bias folded ----
#pragma unroll
    for (int nh = 0; nh < 2; ++nh) {
#pragma unroll
        for (int in = 0; in < 2; ++in) {
            const int col = bColN + nh * 128 + wn * 32 + in * 16 + r;
            const float bia = B1[col] - B2[col];
#pragma unroll
            for (int mh = 0; mh < 2; ++mh) {
#pragma unroll
                for (int im = 0; im < 4; ++im) {
                    const int row0 = bRowM + mh * 128 + wm * 64 + im * 16 + q * 4;
                    const f32x4 v = acc[mh][nh][im][in];
#pragma unroll
                    for (int j = 0; j < 4; ++j)
                        C[(size_t)(row0 + j) * DIM_N + col] = v[j] + bia;
                }
            }
        }
    }
#undef STAGE_A
#undef STAGE_B
}

// ---------------- launch ----------------

extern "C" void kernel_launch(void* const* d_in, const int* in_sizes, int n_in,
                              void* d_out, int out_size, void* d_ws, size_t ws_size,
                              hipStream_t stream) {
    const float* x  = (const float*)d_in[0];
    const float* W1 = (const float*)d_in[1];
    const float* W2 = (const float*)d_in[2];
    const float* b1 = (const float*)d_in[3];
    const float* b2 = (const float*)d_in[4];
    float* out = (float*)d_out;

    // workspace layout: Xh (64 MiB) | Wh (32 MiB)
    _Float16* Xh = (_Float16*)d_ws;
    _Float16* Wh = (_Float16*)((char*)d_ws + (size_t)67108864);
    (void)ws_size; (void)in_sizes; (void)n_in; (void)out_size;

    // fused conversions: x->f16 and sign(W1)-sign(W2)->f16, 16B loads+stores
    cvt_fused<<<2048, 256, 0, stream>>>((const float4*)x, (const float4*)W1,
                                        (const float4*)W2, (f16x8*)Xh, (f16x8*)Wh);

    // GEMM: 512 blocks of 512 threads, 256x256 tiles (32 M-tiles x 16 N-tiles)
    ternary_gemm<<<512, 512, 0, stream>>>(Xh, Wh, b1, b2, out);
}